// Round 4
// baseline (72.388 us; speedup 1.0000x reference)
//
#include <hip/hip_runtime.h>
#include <float.h>

#define NCH  128
#define TLEN 500
// p0 = 500//3 = 166, p1 = 2*500//3 = 333
// n0 = int(0.2*500) = 100, n1 = int(0.35*500) = 175
#define P0 166
#define P1 333
#define N0 100
#define N1 175

// ---- DPP row-rotate (within 16-lane row) helpers: VALU pipe, no DS ----
// dpp_ctrl ROW_ROR_n = 0x120 | n
template<int CTRL>
__device__ __forceinline__ float dpp_rorf(float v) {
    const int s = __float_as_int(v);
    const int d = __builtin_amdgcn_update_dpp(s, s, CTRL, 0xF, 0xF, false);
    return __int_as_float(d);
}
template<int CTRL>
__device__ __forceinline__ int dpp_rori(int v) {
    return __builtin_amdgcn_update_dpp(v, v, CTRL, 0xF, 0xF, false);
}

__device__ __forceinline__ float wave_sum(float v) {
#pragma unroll
    for (int m = 32; m; m >>= 1) v += __shfl_xor(v, m, 64);
    return v;
}
__device__ __forceinline__ float wave_min(float v) {
#pragma unroll
    for (int m = 32; m; m >>= 1) v = fminf(v, __shfl_xor(v, m, 64));
    return v;
}
__device__ __forceinline__ float wave_max(float v) {
#pragma unroll
    for (int m = 32; m; m >>= 1) v = fmaxf(v, __shfl_xor(v, m, 64));
    return v;
}

// One block == one batch. 4 waves x 4 groups of 16 lanes; each 16-lane group
// reduces one channel per pass (8 passes -> 128 channels). Loads are 256B
// contiguous per group; in-group reduction is 4 DPP row_ror steps (pure VALU).
__global__ __launch_bounds__(256) void erp_feats_kernel(
    const float* __restrict__ eeg, float* __restrict__ out) {
    const int b    = blockIdx.x;
    const int tid  = threadIdx.x;
    const int wid  = tid >> 6;        // wave 0..3
    const int lane = tid & 63;
    const int g    = lane >> 4;       // group 0..3 within wave
    const int l    = lane & 15;       // lane 0..15 within group

    __shared__ float s_lat[NCH], s_amp[NCH], s_n2[NCH], s_alpha[NCH], s_beta[NCH];

    const float* __restrict__ base = eeg + (size_t)b * NCH * TLEN;

#pragma unroll 1
    for (int p = 0; p < 8; ++p) {
        const int c = p * 16 + wid * 4 + g;
        const float* __restrict__ ch = base + (size_t)c * TLEN;

        float asum  = 0.0f;           // sum x^2 over [0,166)
        float bsum  = 0.0f;           // sum x^2 over [166,333)
        float n2min = FLT_MAX;        // min over [100,175)
        float pmax  = -FLT_MAX;       // max over [166,333)
        int   pidx  = P0;             // global t of first max

        // k = 0..4: float4 index i = 16k + l in [0,80) -> t in [0,320), all valid
#pragma unroll
        for (int k = 0; k < 5; ++k) {
            const int i = k * 16 + l;
            const float4 v = *reinterpret_cast<const float4*>(ch + 4 * i);
            const float e[4] = {v.x, v.y, v.z, v.w};
            const int t0 = 4 * i;
#pragma unroll
            for (int j = 0; j < 4; ++j) {
                const int t = t0 + j;
                const float x  = e[j];
                const float xx = x * x;
                if (t < P0) {
                    asum += xx;
                } else {
                    bsum += xx;
                    if (x > pmax) { pmax = x; pidx = t; }   // strict >: first occurrence
                }
                if (t >= N0 && t < N1) n2min = fminf(n2min, x);
            }
        }
        // tail: i = 80 + l for l < 4 -> t in [320,336), keep t < 333
        if (l < 4) {
            const int i = 80 + l;
            const float4 v = *reinterpret_cast<const float4*>(ch + 4 * i);
            const float e[4] = {v.x, v.y, v.z, v.w};
            const int t0 = 4 * i;
#pragma unroll
            for (int j = 0; j < 4; ++j) {
                const int t = t0 + j;
                if (t < P1) {
                    const float x = e[j];
                    bsum += x * x;
                    if (x > pmax) { pmax = x; pidx = t; }
                }
            }
        }

        // 16-lane reduction via DPP row rotations (ror 8,4,2,1):
        // rotation sets are disjoint across steps -> exact fold of all 16 lanes.
#define RED_STEP(CTRL)                                                       \
        {                                                                    \
            asum  += dpp_rorf<CTRL>(asum);                                   \
            bsum  += dpp_rorf<CTRL>(bsum);                                   \
            n2min  = fminf(n2min, dpp_rorf<CTRL>(n2min));                    \
            const float om = dpp_rorf<CTRL>(pmax);                           \
            const int   oi = dpp_rori<CTRL>(pidx);                           \
            if (om > pmax || (om == pmax && oi < pidx)) { pmax = om; pidx = oi; } \
        }
        RED_STEP(0x128)   // ror 8
        RED_STEP(0x124)   // ror 4
        RED_STEP(0x122)   // ror 2
        RED_STEP(0x121)   // ror 1
#undef RED_STEP

        if (l == 0) {
            s_lat[c]   = (float)pidx / 100.0f;   // (p0 + peak_idx)/SFREQ, pidx is global t
            s_amp[c]   = pmax;
            s_n2[c]    = n2min;
            s_alpha[c] = asum / 166.0f;          // mean over [0,166)
            s_beta[c]  = bsum / 167.0f;          // mean over [166,333)
        }
    }

    __syncthreads();

    // ---- channel statistics (wave 0 only; lane handles ch lane and lane+64) ----
    if (wid == 0) {
        const float lat0 = s_lat[lane],   lat1 = s_lat[lane + 64];
        const float amp0 = s_amp[lane],   amp1 = s_amp[lane + 64];
        const float n20  = s_n2[lane],    n21  = s_n2[lane + 64];
        const float al0  = s_alpha[lane], al1  = s_alpha[lane + 64];
        const float be0  = s_beta[lane],  be1  = s_beta[lane + 64];

        const float inv_n = 1.0f / 128.0f;
        const float inv_m = 1.0f / 127.0f;   // ddof=1

        const float lat_mean = wave_sum(lat0 + lat1) * inv_n;
        const float amp_mean = wave_sum(amp0 + amp1) * inv_n;
        const float n2_mean  = wave_sum(n20 + n21)   * inv_n;
        const float al_mean  = wave_sum(al0 + al1)   * inv_n;
        const float be_mean  = wave_sum(be0 + be1)   * inv_n;
        const float axl_mean = wave_sum(amp0 * lat0 + amp1 * lat1) * inv_n;

        const float dl0 = lat0 - lat_mean, dl1 = lat1 - lat_mean;
        const float lat_std = sqrtf(wave_sum(dl0 * dl0 + dl1 * dl1) * inv_m);
        const float dn0 = n20 - n2_mean, dn1 = n21 - n2_mean;
        const float n2_std = sqrtf(wave_sum(dn0 * dn0 + dn1 * dn1) * inv_m);
        const float da0 = al0 - al_mean, da1 = al1 - al_mean;
        const float al_std = sqrtf(wave_sum(da0 * da0 + da1 * da1) * inv_m);
        const float db0 = be0 - be_mean, db1 = be1 - be_mean;
        const float be_std = sqrtf(wave_sum(db0 * db0 + db1 * db1) * inv_m);

        const float amp_max = wave_max(fmaxf(amp0, amp1));
        const float n2_min  = wave_min(fminf(n20, n21));
        const float al_max  = wave_max(fmaxf(al0, al1));

        if (lane == 0) {
            float* o = out + (size_t)b * 13;
            o[0]  = lat_mean;
            o[1]  = lat_std;
            o[2]  = amp_mean;
            o[3]  = amp_max;
            o[4]  = axl_mean;
            o[5]  = n2_mean;
            o[6]  = n2_std;
            o[7]  = n2_min;
            o[8]  = al_mean;
            o[9]  = al_std;
            o[10] = al_max;
            o[11] = be_mean;
            o[12] = be_std;
        }
    }
}

extern "C" void kernel_launch(void* const* d_in, const int* in_sizes, int n_in,
                              void* d_out, int out_size, void* d_ws, size_t ws_size,
                              hipStream_t stream) {
    const float* eeg = (const float*)d_in[0];
    float* out = (float*)d_out;
    const int B = in_sizes[0] / (NCH * TLEN);   // 2048
    erp_feats_kernel<<<dim3(B), dim3(256), 0, stream>>>(eeg, out);
}

// Round 5
// 72.204 us; speedup vs baseline: 1.0025x; 1.0025x over previous
//
#include <hip/hip_runtime.h>
#include <float.h>

#define NCH  128
#define TLEN 500
// p0 = 500//3 = 166, p1 = 2*500//3 = 333
// n0 = int(0.2*500) = 100, n1 = int(0.35*500) = 175
#define P0 166

// ---- DPP row-rotate (within 16-lane row): VALU pipe, no DS ----
template<int CTRL>
__device__ __forceinline__ float dpp_rorf(float v) {
    const int s = __float_as_int(v);
    const int d = __builtin_amdgcn_update_dpp(s, s, CTRL, 0xF, 0xF, false);
    return __int_as_float(d);
}
template<int CTRL>
__device__ __forceinline__ int dpp_rori(int v) {
    return __builtin_amdgcn_update_dpp(v, v, CTRL, 0xF, 0xF, false);
}

__device__ __forceinline__ float wave_sum(float v) {
#pragma unroll
    for (int m = 32; m; m >>= 1) v += __shfl_xor(v, m, 64);
    return v;
}
__device__ __forceinline__ float wave_min(float v) {
#pragma unroll
    for (int m = 32; m; m >>= 1) v = fminf(v, __shfl_xor(v, m, 64));
    return v;
}
__device__ __forceinline__ float wave_max(float v) {
#pragma unroll
    for (int m = 32; m; m >>= 1) v = fmaxf(v, __shfl_xor(v, m, 64));
    return v;
}

// Per-pass reduction for one channel, with k-specialized window logic.
// t = 64k + 4l + j ; u = 4l + j.
//  k=0: t in [0,64)    -> alpha only
//  k=1: t in [64,128)  -> alpha; n2 iff l>=9  (t>=100)
//  k=2: t in [128,192) -> alpha iff u<38 (t<166) else beta+argmax; n2 iff u<47 (t<175)
//  k=3: t in [192,256) -> beta+argmax
//  k=4: t in [256,320) -> beta+argmax
//  tail (l<4): t = 320+u, valid iff u<13 (t<333) -> beta+argmax
__device__ __forceinline__ void compute_pass(
    float4 s0, float4 s1, float4 s2, float4 s3, float4 s4, float4 s5,
    int c, int l, int l4, bool lt4,
    float* __restrict__ s_lat, float* __restrict__ s_amp, float* __restrict__ s_n2,
    float* __restrict__ s_alpha, float* __restrict__ s_beta) {

    float asum  = 0.0f;
    float bsum  = 0.0f;
    float n2min = FLT_MAX;
    float pmax  = -FLT_MAX;
    int   pidx  = 0x7fffffff;

#define PMAXU(x, t) { if ((x) > pmax) { pmax = (x); pidx = (t); } }

    {   // k = 0: pure alpha
        const float e[4] = {s0.x, s0.y, s0.z, s0.w};
#pragma unroll
        for (int j = 0; j < 4; ++j) asum = fmaf(e[j], e[j], asum);
    }
    {   // k = 1: alpha; n2 iff l>=9
        const float e[4] = {s1.x, s1.y, s1.z, s1.w};
#pragma unroll
        for (int j = 0; j < 4; ++j) asum = fmaf(e[j], e[j], asum);
        if (l >= 9) {
            n2min = fminf(n2min, fminf(fminf(e[0], e[1]), fminf(e[2], e[3])));
        }
    }
    {   // k = 2: split at u=38 (alpha/beta+argmax), n2 iff u<47
        const float e[4] = {s2.x, s2.y, s2.z, s2.w};
#pragma unroll
        for (int j = 0; j < 4; ++j) {
            const int u = l4 + j;
            const float x = e[j];
            if (u < 38) {
                asum = fmaf(x, x, asum);
            } else {
                bsum = fmaf(x, x, bsum);
                PMAXU(x, 128 + u);
            }
            if (u < 47) n2min = fminf(n2min, x);
        }
    }
    {   // k = 3: beta + argmax
        const float e[4] = {s3.x, s3.y, s3.z, s3.w};
#pragma unroll
        for (int j = 0; j < 4; ++j) {
            const float x = e[j];
            bsum = fmaf(x, x, bsum);
            PMAXU(x, 192 + l4 + j);
        }
    }
    {   // k = 4: beta + argmax
        const float e[4] = {s4.x, s4.y, s4.z, s4.w};
#pragma unroll
        for (int j = 0; j < 4; ++j) {
            const float x = e[j];
            bsum = fmaf(x, x, bsum);
            PMAXU(x, 256 + l4 + j);
        }
    }
    if (lt4) {  // tail: t = 320+u, u < 13
        const float e[4] = {s5.x, s5.y, s5.z, s5.w};
#pragma unroll
        for (int j = 0; j < 4; ++j) {
            const int u = l4 + j;
            if (u < 13) {
                const float x = e[j];
                bsum = fmaf(x, x, bsum);
                PMAXU(x, 320 + u);
            }
        }
    }
#undef PMAXU

    // 16-lane fold via DPP row rotations (disjoint sets: 8,4,2,1)
#define RED_STEP(CTRL)                                                        \
    {                                                                         \
        asum  += dpp_rorf<CTRL>(asum);                                        \
        bsum  += dpp_rorf<CTRL>(bsum);                                        \
        n2min  = fminf(n2min, dpp_rorf<CTRL>(n2min));                         \
        const float om = dpp_rorf<CTRL>(pmax);                                \
        const int   oi = dpp_rori<CTRL>(pidx);                                \
        if (om > pmax || (om == pmax && oi < pidx)) { pmax = om; pidx = oi; } \
    }
    RED_STEP(0x128)
    RED_STEP(0x124)
    RED_STEP(0x122)
    RED_STEP(0x121)
#undef RED_STEP

    if (l == 0) {
        s_lat[c]   = (float)pidx / 100.0f;   // (p0 + peak_idx)/SFREQ
        s_amp[c]   = pmax;
        s_n2[c]    = n2min;
        s_alpha[c] = asum / 166.0f;
        s_beta[c]  = bsum / 167.0f;
    }
}

// One block == one batch. 4 waves x 4 groups of 16 lanes; each group reduces
// one channel per pass (8 passes). 2-deep software pipeline: pass p+1's loads
// are issued before pass p's compute.
__global__ __launch_bounds__(256) void erp_feats_kernel(
    const float* __restrict__ eeg, float* __restrict__ out) {
    const int b    = blockIdx.x;
    const int tid  = threadIdx.x;
    const int wid  = tid >> 6;
    const int lane = tid & 63;
    const int g    = lane >> 4;
    const int l    = lane & 15;
    const int l4   = l << 2;
    const bool lt4 = (l < 4);
    const int cbase = (wid << 2) + g;

    __shared__ float s_lat[NCH], s_amp[NCH], s_n2[NCH], s_alpha[NCH], s_beta[NCH];

    const float* __restrict__ base = eeg + (size_t)b * NCH * TLEN;

#define ISSUE(d, P)                                                           \
    {                                                                         \
        const float* __restrict__ _ch = base + (size_t)((P) * 16 + cbase) * TLEN; \
        d##0 = *reinterpret_cast<const float4*>(_ch + l4);                    \
        d##1 = *reinterpret_cast<const float4*>(_ch +  64 + l4);              \
        d##2 = *reinterpret_cast<const float4*>(_ch + 128 + l4);              \
        d##3 = *reinterpret_cast<const float4*>(_ch + 192 + l4);              \
        d##4 = *reinterpret_cast<const float4*>(_ch + 256 + l4);              \
        if (lt4) d##5 = *reinterpret_cast<const float4*>(_ch + 320 + l4);     \
    }
#define DO_COMPUTE(d, P)                                                      \
    compute_pass(d##0, d##1, d##2, d##3, d##4, d##5, (P) * 16 + cbase,        \
                 l, l4, lt4, s_lat, s_amp, s_n2, s_alpha, s_beta);

    float4 a0, a1, a2, a3, a4, a5{};
    float4 b0, b1, b2, b3, b4, b5{};

    ISSUE(a, 0)
    ISSUE(b, 1) DO_COMPUTE(a, 0)
    ISSUE(a, 2) DO_COMPUTE(b, 1)
    ISSUE(b, 3) DO_COMPUTE(a, 2)
    ISSUE(a, 4) DO_COMPUTE(b, 3)
    ISSUE(b, 5) DO_COMPUTE(a, 4)
    ISSUE(a, 6) DO_COMPUTE(b, 5)
    ISSUE(b, 7) DO_COMPUTE(a, 6)
    DO_COMPUTE(b, 7)

#undef ISSUE
#undef DO_COMPUTE

    __syncthreads();

    // ---- channel statistics (wave 0 only) ----
    if (wid == 0) {
        const float lat0 = s_lat[lane],   lat1 = s_lat[lane + 64];
        const float amp0 = s_amp[lane],   amp1 = s_amp[lane + 64];
        const float n20  = s_n2[lane],    n21  = s_n2[lane + 64];
        const float al0  = s_alpha[lane], al1  = s_alpha[lane + 64];
        const float be0  = s_beta[lane],  be1  = s_beta[lane + 64];

        const float inv_n = 1.0f / 128.0f;
        const float inv_m = 1.0f / 127.0f;   // ddof=1

        const float lat_mean = wave_sum(lat0 + lat1) * inv_n;
        const float amp_mean = wave_sum(amp0 + amp1) * inv_n;
        const float n2_mean  = wave_sum(n20 + n21)   * inv_n;
        const float al_mean  = wave_sum(al0 + al1)   * inv_n;
        const float be_mean  = wave_sum(be0 + be1)   * inv_n;
        const float axl_mean = wave_sum(amp0 * lat0 + amp1 * lat1) * inv_n;

        const float dl0 = lat0 - lat_mean, dl1 = lat1 - lat_mean;
        const float lat_std = sqrtf(wave_sum(dl0 * dl0 + dl1 * dl1) * inv_m);
        const float dn0 = n20 - n2_mean, dn1 = n21 - n2_mean;
        const float n2_std = sqrtf(wave_sum(dn0 * dn0 + dn1 * dn1) * inv_m);
        const float da0 = al0 - al_mean, da1 = al1 - al_mean;
        const float al_std = sqrtf(wave_sum(da0 * da0 + da1 * da1) * inv_m);
        const float db0 = be0 - be_mean, db1 = be1 - be_mean;
        const float be_std = sqrtf(wave_sum(db0 * db0 + db1 * db1) * inv_m);

        const float amp_max = wave_max(fmaxf(amp0, amp1));
        const float n2_min  = wave_min(fminf(n20, n21));
        const float al_max  = wave_max(fmaxf(al0, al1));

        if (lane == 0) {
            float* o = out + (size_t)b * 13;
            o[0]  = lat_mean;
            o[1]  = lat_std;
            o[2]  = amp_mean;
            o[3]  = amp_max;
            o[4]  = axl_mean;
            o[5]  = n2_mean;
            o[6]  = n2_std;
            o[7]  = n2_min;
            o[8]  = al_mean;
            o[9]  = al_std;
            o[10] = al_max;
            o[11] = be_mean;
            o[12] = be_std;
        }
    }
}

extern "C" void kernel_launch(void* const* d_in, const int* in_sizes, int n_in,
                              void* d_out, int out_size, void* d_ws, size_t ws_size,
                              hipStream_t stream) {
    const float* eeg = (const float*)d_in[0];
    float* out = (float*)d_out;
    const int B = in_sizes[0] / (NCH * TLEN);   // 2048
    erp_feats_kernel<<<dim3(B), dim3(256), 0, stream>>>(eeg, out);
}